// Round 7
// baseline (514.519 us; speedup 1.0000x reference)
//
#include <hip/hip_runtime.h>

// B=4,S=2048,H=16,D=64. scores/8, mask->1e-20(~0), softmax, PV.
// Round 7: pipelined fused kernel. Mask is compressed chunk-by-chunk (256 kv)
// INSIDE the flash loop: each step issues 16 NT lane-contiguous i32x4 loads of
// chunk j+1, computes on chunk j's bits (LDS double-buffer), then packs the
// landed loads. HBM mask stream overlaps MFMA/VALU; K/V frags from L2 (prepack).
// Masked positions -> exp2(0)=1, matching ref's 1e-20 pre-softmax semantics.

typedef __attribute__((ext_vector_type(8))) short short8;
typedef __attribute__((ext_vector_type(4))) float f32x4;
typedef __attribute__((ext_vector_type(4))) int   i32x4;
typedef unsigned int       u32;
typedef unsigned long long u64;

#define MFMA(a, b, c) __builtin_amdgcn_mfma_f32_16x16x32_bf16((a), (b), (c), 0, 0, 0)

static __device__ __forceinline__ short f2bf(float f) {
    __bf16 h = (__bf16)f;
    return __builtin_bit_cast(short, h);
}

static __device__ __forceinline__ u32 nib4(i32x4 m) {
    return (m[0] != 0 ? 1u : 0u) | (m[1] != 0 ? 2u : 0u) |
           (m[2] != 0 ? 4u : 0u) | (m[3] != 0 ? 8u : 0u);
}

constexpr int S_ = 2048, HD_ = 1024, STEPS_ = 32;
constexpr long KP_ELEMS = 64L * 32 * 4 * 2 * 64 * 8;   // 8,388,608 bf16 per tensor

// ---- prepack: thread t packs K-fragment t and V-fragment t (same as rounds 2-6).
__global__ __launch_bounds__(256) void prepack_kv(const float* __restrict__ K,
                                                  const float* __restrict__ V,
                                                  short* __restrict__ Kp,
                                                  short* __restrict__ Vp) {
    int t = blockIdx.x * 256 + threadIdx.x;
    int lane = t & 63, hf = (t >> 6) & 1, kt = (t >> 7) & 3, step = (t >> 9) & 31, bh = t >> 14;
    int g = lane >> 4, c = lane & 15, b = bh >> 4, h = bh & 15;

    {   // K: lane holds K[b, step*64+kt*16+c, h, hf*32+g*8 .. +7]
        int row = step * 64 + kt * 16 + c;
        const float* src = K + (long)(b * S_ + row) * HD_ + h * 64 + hf * 32 + g * 8;
        f32x4 x0 = *(const f32x4*)src, x1 = *(const f32x4*)(src + 4);
        short8 o;
        o[0] = f2bf(x0[0]); o[1] = f2bf(x0[1]); o[2] = f2bf(x0[2]); o[3] = f2bf(x0[3]);
        o[4] = f2bf(x1[0]); o[5] = f2bf(x1[1]); o[6] = f2bf(x1[2]); o[7] = f2bf(x1[3]);
        *(short8*)(Kp + (long)t * 8) = o;
    }
    {   // V (kt plays dt): kappa-ordered V^T fragment
        int col = kt * 16 + c, row0 = step * 64 + hf * 32;
        const float* vb = V + (long)(b * S_) * HD_ + h * 64 + col;
        short8 o;
#pragma unroll
        for (int i = 0; i < 8; ++i) {
            int row = row0 + ((i < 4) ? g * 4 + i : 16 + g * 4 + (i - 4));
            o[i] = f2bf(vb[(long)row * HD_]);
        }
        *(short8*)(Vp + (long)t * 8) = o;
    }
}

// ---- fused pipelined attention: 512 blocks x 256 thr; wave owns 64 q-rows.
// Per-wave LDS bit-table, double-buffered per 256-kv chunk (u32 units):
//   buf b (b=chunk&1) at sw[b*1024 + rg*64 + ((l + rg*4) & 63)], rg=row>>2,
//   byte (row&3) bit i = mask(q0+row, chunk*256 + l*4 + i).
__global__ __launch_bounds__(256, 2)
void attn_fused3(const float* __restrict__ Q, const short* __restrict__ Kp,
                 const short* __restrict__ Vp, const int* __restrict__ M,
                 float* __restrict__ O)
{
    const float QSCALE = 0.125f * 1.44269504088896340736f;  // 1/sqrt(64) * log2(e)

    __shared__ u32 sbits[8192];   // 32 KiB: 4 waves x 2 bufs x 1024 u32

    // XCD swizzle: XCD i gets bh 8i..8i+7; all 8 q-blocks of a head co-resident
    int orig = blockIdx.x;
    int wg   = (orig & 7) * 64 + (orig >> 3);
    int bh   = wg >> 3, qb = wg & 7;
    int b    = bh >> 4, h = bh & 15;

    int lane = threadIdx.x & 63, wave = threadIdx.x >> 6;
    int g = lane >> 4, c = lane & 15;
    int q0 = qb * 256 + wave * 64;

    u32* sw = sbits + wave * 2048;

    const float* qbase = Q + (long)(b * S_) * HD_ + h * 64;
    const int*   mbase = M + ((long)bh << 22);
    float*       obase = O + (long)(b * S_) * HD_ + h * 64;
    const short* kpb   = Kp + (long)bh * STEPS_ * 4096;
    const short* vpb   = Vp + (long)bh * STEPS_ * 4096;

    // Q fragments (B-operand): lane holds Q[q0+qt*16+c][hf*32+g*8 ..+7] * QSCALE
    short8 qf[4][2];
#pragma unroll
    for (int qt = 0; qt < 4; ++qt) {
        const float* qr = qbase + (long)(q0 + qt * 16 + c) * HD_;
#pragma unroll
        for (int hf = 0; hf < 2; ++hf) {
            f32x4 x0 = *(const f32x4*)(qr + hf * 32 + g * 8);
            f32x4 x1 = *(const f32x4*)(qr + hf * 32 + g * 8 + 4);
            short8 t;
            t[0] = f2bf(x0[0] * QSCALE); t[1] = f2bf(x0[1] * QSCALE);
            t[2] = f2bf(x0[2] * QSCALE); t[3] = f2bf(x0[3] * QSCALE);
            t[4] = f2bf(x1[0] * QSCALE); t[5] = f2bf(x1[1] * QSCALE);
            t[6] = f2bf(x1[2] * QSCALE); t[7] = f2bf(x1[3] * QSCALE);
            qf[qt][hf] = t;
        }
    }

    // ---- prologue: compress chunk 0 -> buf 0 (lane-contiguous NT stream)
    {
        const int* mr = mbase + ((long)q0 << 11) + lane * 4;
#pragma unroll 4
        for (int rg = 0; rg < 16; ++rg) {
            u32 w = 0;
#pragma unroll
            for (int rr = 0; rr < 4; ++rr) {
                i32x4 m = __builtin_nontemporal_load(
                    (const i32x4*)(mr + ((long)(rg * 4 + rr) << 11)));
                w |= nib4(m) << (rr * 8);
            }
            sw[rg * 64 + ((lane + rg * 4) & 63)] = w;
        }
    }

    f32x4 acc[4][4];
#pragma unroll
    for (int qt = 0; qt < 4; ++qt)
#pragma unroll
        for (int dt = 0; dt < 4; ++dt) acc[qt][dt] = (f32x4){0.f, 0.f, 0.f, 0.f};
    float lsum[4] = {0.f, 0.f, 0.f, 0.f};

    int shft = (c & 3) * 8;

#pragma unroll 1
    for (int step = 0; step < STEPS_; ++step) {
        int j    = step >> 2;
        int sL   = step & 3;
        int bufr = (j & 1) << 10;

        // 1) K/V fragment loads (L2) — issued FIRST so the compute's counted
        //    vmcnt wait does not drain the mask prefetch behind them.
        const short* kp = kpb + (long)step * 4096;
        const short* vp = vpb + (long)step * 4096;
        short8 kf[4][2], vf[4][2];
#pragma unroll
        for (int kt = 0; kt < 4; ++kt)
#pragma unroll
            for (int hf = 0; hf < 2; ++hf) {
                kf[kt][hf] = *(const short8*)(kp + ((kt * 2 + hf) * 64 + lane) * 8);
                vf[kt][hf] = *(const short8*)(vp + ((kt * 2 + hf) * 64 + lane) * 8);
            }

        // 2) chunk j+1 mask prefetch: rows sL*16 .. sL*16+15 (16 x 1KiB wave-loads)
        i32x4 pm[16];
        bool pre = (j < 7);
        if (pre) {
            const int* mc = mbase + ((long)q0 << 11) + (j + 1) * 256 + lane * 4;
#pragma unroll
            for (int t = 0; t < 16; ++t)
                pm[t] = __builtin_nontemporal_load(
                    (const i32x4*)(mc + ((long)(sL * 16 + t) << 11)));
        }
        __builtin_amdgcn_sched_barrier(0);

        // 3) compute this step on chunk j's bits
#pragma unroll
        for (int qt = 0; qt < 4; ++qt) {
            f32x4 st[4];
#pragma unroll
            for (int kt = 0; kt < 4; ++kt) {
                f32x4 z = (f32x4){0.f, 0.f, 0.f, 0.f};
                z = MFMA(kf[kt][0], qf[qt][0], z);
                z = MFMA(kf[kt][1], qf[qt][1], z);
                st[kt] = z;   // kv = step*64+kt*16+g*4+r, q = q0+qt*16+c (log2e-scaled)
            }

            int rgq = qt * 4 + (c >> 2);
            u32 fld[4];
#pragma unroll
            for (int kt = 0; kt < 4; ++kt) {
                int lw = sL * 16 + kt * 4 + g;
                fld[kt] = sw[bufr + rgq * 64 + ((lw + rgq * 4) & 63)] >> shft;
            }

            float p[4][4];
            float s = 0.f;
#pragma unroll
            for (int kt = 0; kt < 4; ++kt) {
#pragma unroll
                for (int r = 0; r < 4; ++r) {
                    u32 bit = (fld[kt] >> r) & 1u;
                    float val = bit ? st[kt][r] : 0.0f;   // masked -> exp2(0)=1
                    float e = exp2f(val);
                    p[kt][r] = e;
                    s += e;
                }
            }
            lsum[qt] += s;

            short8 pb0, pb1;
            pb0[0] = f2bf(p[0][0]); pb0[1] = f2bf(p[0][1]); pb0[2] = f2bf(p[0][2]); pb0[3] = f2bf(p[0][3]);
            pb0[4] = f2bf(p[1][0]); pb0[5] = f2bf(p[1][1]); pb0[6] = f2bf(p[1][2]); pb0[7] = f2bf(p[1][3]);
            pb1[0] = f2bf(p[2][0]); pb1[1] = f2bf(p[2][1]); pb1[2] = f2bf(p[2][2]); pb1[3] = f2bf(p[2][3]);
            pb1[4] = f2bf(p[3][0]); pb1[5] = f2bf(p[3][1]); pb1[6] = f2bf(p[3][2]); pb1[7] = f2bf(p[3][3]);

#pragma unroll
            for (int dt = 0; dt < 4; ++dt) {
                acc[qt][dt] = MFMA(vf[dt][0], pb0, acc[qt][dt]);
                acc[qt][dt] = MFMA(vf[dt][1], pb1, acc[qt][dt]);
            }
        }

        // 4) pack the landed prefetch into buf (j+1)&1
        if (pre) {
            int bufw = ((j + 1) & 1) << 10;
#pragma unroll
            for (int t4 = 0; t4 < 4; ++t4) {
                int rg = sL * 4 + t4;
                u32 w = 0;
#pragma unroll
                for (int rr = 0; rr < 4; ++rr)
                    w |= nib4(pm[t4 * 4 + rr]) << (rr * 8);
                sw[bufw + rg * 64 + ((lane + rg * 4) & 63)] = w;
            }
        }
    }

    // epilogue: reduce row sums across g-groups, normalize, store
#pragma unroll
    for (int qt = 0; qt < 4; ++qt) {
        float t0 = lsum[qt];
        t0 += __shfl_xor(t0, 16);
        t0 += __shfl_xor(t0, 32);
        float inv = 1.0f / t0;
        float* orow = obase + (long)(q0 + qt * 16 + c) * HD_;
#pragma unroll
        for (int dt = 0; dt < 4; ++dt) {
            f32x4 o = acc[qt][dt] * inv;
            __builtin_nontemporal_store(o, (f32x4*)(orow + dt * 16 + g * 4));
        }
    }
}

// ---- fallback (only if ws too small): round-1 style fused kernel ----
__global__ __launch_bounds__(256, 2)
void attn_fwd(const float* __restrict__ Q, const float* __restrict__ K,
              const float* __restrict__ V, const int* __restrict__ M,
              float* __restrict__ O)
{
    const float QSCALE = 0.125f * 1.44269504088896340736f;
    int orig = blockIdx.x;
    int wg   = (orig & 7) * 64 + (orig >> 3);
    int bh   = wg >> 3, qb = wg & 7;
    int b    = bh >> 4, h = bh & 15;
    int lane = threadIdx.x & 63, wave = threadIdx.x >> 6;
    int g = lane >> 4, c = lane & 15;
    int q0 = qb * 256 + wave * 64;

    const float* qbase = Q + (long)(b * S_) * HD_ + h * 64;
    const float* kbase = K + (long)(b * S_) * HD_ + h * 64;
    const float* vbase = V + (long)(b * S_) * HD_ + h * 64;
    const int*   mbase = M + ((long)bh << 22);
    float*       obase = O + (long)(b * S_) * HD_ + h * 64;

    short8 qf[4][2];
#pragma unroll
    for (int qt = 0; qt < 4; ++qt) {
        const float* qr = qbase + (long)(q0 + qt * 16 + c) * HD_;
#pragma unroll
        for (int hf = 0; hf < 2; ++hf) {
            f32x4 x0 = *(const f32x4*)(qr + hf * 32 + g * 8);
            f32x4 x1 = *(const f32x4*)(qr + hf * 32 + g * 8 + 4);
            short8 t;
            t[0] = f2bf(x0[0] * QSCALE); t[1] = f2bf(x0[1] * QSCALE);
            t[2] = f2bf(x0[2] * QSCALE); t[3] = f2bf(x0[3] * QSCALE);
            t[4] = f2bf(x1[0] * QSCALE); t[5] = f2bf(x1[1] * QSCALE);
            t[6] = f2bf(x1[2] * QSCALE); t[7] = f2bf(x1[3] * QSCALE);
            qf[qt][hf] = t;
        }
    }

    f32x4 acc[4][4];
#pragma unroll
    for (int qt = 0; qt < 4; ++qt)
#pragma unroll
        for (int dt = 0; dt < 4; ++dt) acc[qt][dt] = (f32x4){0.f, 0.f, 0.f, 0.f};
    float lsum[4] = {0.f, 0.f, 0.f, 0.f};

#pragma unroll 1
    for (int step = 0; step < STEPS_; ++step) {
        int kv0 = step * 64;
        short8 kf[4][2];
#pragma unroll
        for (int kt = 0; kt < 4; ++kt) {
            const float* kr = kbase + (long)(kv0 + kt * 16 + c) * HD_;
#pragma unroll
            for (int hf = 0; hf < 2; ++hf) {
                f32x4 x0 = *(const f32x4*)(kr + hf * 32 + g * 8);
                f32x4 x1 = *(const f32x4*)(kr + hf * 32 + g * 8 + 4);
                short8 t;
                t[0] = f2bf(x0[0]); t[1] = f2bf(x0[1]); t[2] = f2bf(x0[2]); t[3] = f2bf(x0[3]);
                t[4] = f2bf(x1[0]); t[5] = f2bf(x1[1]); t[6] = f2bf(x1[2]); t[7] = f2bf(x1[3]);
                kf[kt][hf] = t;
            }
        }
        short8 vf[4][2];
#pragma unroll
        for (int hf = 0; hf < 2; ++hf) {
            const float* vr[8];
#pragma unroll
            for (int i = 0; i < 4; ++i) {
                vr[i]     = vbase + (long)(kv0 + hf * 32 + g * 4 + i) * HD_ + c;
                vr[4 + i] = vbase + (long)(kv0 + hf * 32 + 16 + g * 4 + i) * HD_ + c;
            }
#pragma unroll
            for (int dt = 0; dt < 4; ++dt) {
                short8 t;
#pragma unroll
                for (int i = 0; i < 8; ++i) t[i] = f2bf(vr[i][dt * 16]);
                vf[dt][hf] = t;
            }
        }
#pragma unroll
        for (int qt = 0; qt < 4; ++qt) {
            f32x4 st[4];
#pragma unroll
            for (int kt = 0; kt < 4; ++kt) {
                f32x4 z = (f32x4){0.f, 0.f, 0.f, 0.f};
                z = MFMA(kf[kt][0], qf[qt][0], z);
                z = MFMA(kf[kt][1], qf[qt][1], z);
                st[kt] = z;
            }
            const int* mrp = mbase + ((long)(q0 + qt * 16 + c) << 11) + kv0 + g * 4;
            float p[4][4];
            float s = 0.f;
#pragma unroll
            for (int kt = 0; kt < 4; ++kt) {
                i32x4 mkv = *(const i32x4*)(mrp + kt * 16);
#pragma unroll
                for (int r = 0; r < 4; ++r) {
                    float val = (mkv[r] != 0) ? st[kt][r] : 0.0f;
                    float e = exp2f(val);
                    p[kt][r] = e;
                    s += e;
                }
            }
            lsum[qt] += s;
            short8 pb0, pb1;
            pb0[0] = f2bf(p[0][0]); pb0[1] = f2bf(p[0][1]); pb0[2] = f2bf(p[0][2]); pb0[3] = f2bf(p[0][3]);
            pb0[4] = f2bf(p[1][0]); pb0[5] = f2bf(p[1][1]); pb0[6] = f2bf(p[1][2]); pb0[7] = f2bf(p[1][3]);
            pb1[0] = f2bf(p[2][0]); pb1[1] = f2bf(p[2][1]); pb1[2] = f2bf(p[2][2]); pb1[3] = f2bf(p[2][3]);
            pb1[4] = f2bf(p[3][0]); pb1[5] = f2bf(p[3][1]); pb1[6] = f2bf(p[3][2]); pb1[7] = f2bf(p[3][3]);
#pragma unroll
            for (int dt = 0; dt < 4; ++dt) {
                acc[qt][dt] = MFMA(vf[dt][0], pb0, acc[qt][dt]);
                acc[qt][dt] = MFMA(vf[dt][1], pb1, acc[qt][dt]);
            }
        }
    }
#pragma unroll
    for (int qt = 0; qt < 4; ++qt) {
        float t0 = lsum[qt];
        t0 += __shfl_xor(t0, 16);
        t0 += __shfl_xor(t0, 32);
        float inv = 1.0f / t0;
        float* orow = obase + (long)(q0 + qt * 16 + c) * HD_;
#pragma unroll
        for (int dt = 0; dt < 4; ++dt) {
            f32x4 o = acc[qt][dt] * inv;
            *(f32x4*)(orow + dt * 16 + g * 4) = o;
        }
    }
}

extern "C" void kernel_launch(void* const* d_in, const int* in_sizes, int n_in,
                              void* d_out, int out_size, void* d_ws, size_t ws_size,
                              hipStream_t stream) {
    const float* q = (const float*)d_in[0];
    const float* k = (const float*)d_in[1];
    const float* v = (const float*)d_in[2];
    const int*   m = (const int*)d_in[3];
    float* out = (float*)d_out;

    size_t need = (size_t)2 * KP_ELEMS * sizeof(short);   // 32 MiB
    if (ws_size >= need) {
        short* Kp = (short*)d_ws;
        short* Vp = Kp + KP_ELEMS;
        prepack_kv<<<dim3(4096), dim3(256), 0, stream>>>(k, v, Kp, Vp);
        attn_fused3<<<dim3(512), dim3(256), 0, stream>>>(q, Kp, Vp, m, out);
    } else {
        attn_fwd<<<dim3(512), dim3(256), 0, stream>>>(q, k, v, m, out);
    }
}

// Round 8
// 242.471 us; speedup vs baseline: 2.1220x; 2.1220x over previous
//
#include <hip/hip_runtime.h>

// B=4,S=2048,H=16,D=64. scores/8, mask->1e-20(~0), softmax, PV.
// Round 8: HBM-bound pipelined kernel using global_load_lds (zero-VGPR mask
// prefetch). Step=32 kv. Per step: load K/V frags (L2), async-stage next step's
// raw mask (8KB/wave) into LDS double-buffer via 8x gll16 with pre-swizzled
// per-lane source (XOR granule swizzle -> conflict-free ds_read_b128), counted
// s_waitcnt vmcnt(8), compute. No barriers, no mask compression, no register
// prefetch. Compute hides under the 1.07GB mask stream.
// Masked positions -> exp2(0)=1, matching ref's 1e-20 pre-softmax semantics.

typedef __attribute__((ext_vector_type(8))) short short8;
typedef __attribute__((ext_vector_type(4))) float f32x4;
typedef __attribute__((ext_vector_type(4))) int   i32x4;
typedef unsigned int u32;

#define MFMA(a, b, c) __builtin_amdgcn_mfma_f32_16x16x32_bf16((a), (b), (c), 0, 0, 0)

static __device__ __forceinline__ short f2bf(float f) {
    __bf16 h = (__bf16)f;
    return __builtin_bit_cast(short, h);
}

static __device__ __forceinline__ void gll16(const int* src, int* dst) {
    __builtin_amdgcn_global_load_lds(
        (const __attribute__((address_space(1))) void*)src,
        (__attribute__((address_space(3))) void*)dst, 16, 0, 0);
}

constexpr int S_ = 2048, HD_ = 1024;
constexpr long KP_ELEMS = 64L * 32 * 4 * 2 * 64 * 8;   // 8,388,608 bf16 per tensor

// ---- prepack: thread t packs K-fragment t and V-fragment t (same as rounds 2-7).
__global__ __launch_bounds__(256) void prepack_kv(const float* __restrict__ K,
                                                  const float* __restrict__ V,
                                                  short* __restrict__ Kp,
                                                  short* __restrict__ Vp) {
    int t = blockIdx.x * 256 + threadIdx.x;
    int lane = t & 63, hf = (t >> 6) & 1, kt = (t >> 7) & 3, step = (t >> 9) & 31, bh = t >> 14;
    int g = lane >> 4, c = lane & 15, b = bh >> 4, h = bh & 15;

    {   // K: lane holds K[b, step*64+kt*16+c, h, hf*32+g*8 .. +7]
        int row = step * 64 + kt * 16 + c;
        const float* src = K + (long)(b * S_ + row) * HD_ + h * 64 + hf * 32 + g * 8;
        f32x4 x0 = *(const f32x4*)src, x1 = *(const f32x4*)(src + 4);
        short8 o;
        o[0] = f2bf(x0[0]); o[1] = f2bf(x0[1]); o[2] = f2bf(x0[2]); o[3] = f2bf(x0[3]);
        o[4] = f2bf(x1[0]); o[5] = f2bf(x1[1]); o[6] = f2bf(x1[2]); o[7] = f2bf(x1[3]);
        *(short8*)(Kp + (long)t * 8) = o;
    }
    {   // V (kt plays dt): kappa-ordered V^T fragment
        int col = kt * 16 + c, row0 = step * 64 + hf * 32;
        const float* vb = V + (long)(b * S_) * HD_ + h * 64 + col;
        short8 o;
#pragma unroll
        for (int i = 0; i < 8; ++i) {
            int row = row0 + ((i < 4) ? g * 4 + i : 16 + g * 4 + (i - 4));
            o[i] = f2bf(vb[(long)row * HD_]);
        }
        *(short8*)(Vp + (long)t * 8) = o;
    }
}

// ---- main kernel: 512 blocks x 256 thr; wave owns 64 q-rows; 64 steps of 32 kv.
// Per-wave LDS: 2 bufs x 2048 ints (8KB). Buf layout in 16B granules:
//   granule (row, gslot) holds mask ints of (q0+row, step*32 + gi*4 .. +3),
//   gi = gslot ^ (row & 7)   [XOR swizzle, staged via pre-swizzled global src].
__global__ __launch_bounds__(256, 2)
void attn_gll(const float* __restrict__ Q, const short* __restrict__ Kp,
              const short* __restrict__ Vp, const int* __restrict__ M,
              float* __restrict__ O)
{
    const float QSCALE = 0.125f * 1.44269504088896340736f;  // 1/sqrt(64) * log2(e)

    __shared__ int smem[16384];   // 64 KiB: 4 waves x 2 bufs x 2048 ints

    // XCD swizzle: XCD i gets bh 8i..8i+7; all 8 q-blocks of a head co-resident
    int orig = blockIdx.x;
    int wg   = (orig & 7) * 64 + (orig >> 3);
    int bh   = wg >> 3, qb = wg & 7;
    int b    = bh >> 4, h = bh & 15;

    int lane = threadIdx.x & 63, wave = threadIdx.x >> 6;
    int g = lane >> 4, c = lane & 15;
    int q0 = qb * 256 + wave * 64;

    int* swv = smem + wave * 4096;

    const float* qbase = Q + (long)(b * S_) * HD_ + h * 64;
    const int*   mbase = M + ((long)bh << 22);
    float*       obase = O + (long)(b * S_) * HD_ + h * 64;
    const short* kpb   = Kp + (long)bh * 32 * 4096;
    const short* vpb   = Vp + (long)bh * 32 * 4096;

    // per-lane gll source base: instr i, step s reads granule for
    // row = i*8 + (lane>>3), gi = (lane&7) ^ ((lane>>3)&7)
    int lrow = lane >> 3;
    int lgi  = (lane & 7) ^ lrow;
    const int* lane_src = mbase + ((long)(q0 + lrow) << 11) + lgi * 4;

    // ---- stage step 0 -> buf 0
#pragma unroll
    for (int i = 0; i < 8; ++i)
        gll16(lane_src + i * 16384, swv + i * 256);

    // ---- Q fragments (B-operand): lane holds Q[q0+qt*16+c][hf*32+g*8 ..+7] * QSCALE
    short8 qf[4][2];
#pragma unroll
    for (int qt = 0; qt < 4; ++qt) {
        const float* qr = qbase + (long)(q0 + qt * 16 + c) * HD_;
#pragma unroll
        for (int hf = 0; hf < 2; ++hf) {
            f32x4 x0 = *(const f32x4*)(qr + hf * 32 + g * 8);
            f32x4 x1 = *(const f32x4*)(qr + hf * 32 + g * 8 + 4);
            short8 t;
            t[0] = f2bf(x0[0] * QSCALE); t[1] = f2bf(x0[1] * QSCALE);
            t[2] = f2bf(x0[2] * QSCALE); t[3] = f2bf(x0[3] * QSCALE);
            t[4] = f2bf(x1[0] * QSCALE); t[5] = f2bf(x1[1] * QSCALE);
            t[6] = f2bf(x1[2] * QSCALE); t[7] = f2bf(x1[3] * QSCALE);
            qf[qt][hf] = t;
        }
    }

    f32x4 acc[4][4];
#pragma unroll
    for (int qt = 0; qt < 4; ++qt)
#pragma unroll
        for (int dt = 0; dt < 4; ++dt) acc[qt][dt] = (f32x4){0.f, 0.f, 0.f, 0.f};
    float lsum[4] = {0.f, 0.f, 0.f, 0.f};

    int c7 = c & 7;
    int gs0 = (g ^ c7) << 2;            // int offset of kt=0 granule within row
    int gs1 = ((4 + g) ^ c7) << 2;      // kt=1

#pragma unroll 1
    for (int s = 0; s < 64; ++s) {
        int s64 = s >> 1, half = s & 1;

        // 1) K/V fragment loads (L2-resident packed layout)
        const short* kp2 = kpb + (long)s64 * 4096 + half * 2048;
        const short* vp2 = vpb + (long)s64 * 4096 + half * 512;
        short8 kf[2][2], vf[4];
#pragma unroll
        for (int kt = 0; kt < 2; ++kt)
#pragma unroll
            for (int hf = 0; hf < 2; ++hf)
                kf[kt][hf] = *(const short8*)(kp2 + kt * 1024 + hf * 512 + lane * 8);
#pragma unroll
        for (int dt = 0; dt < 4; ++dt)
            vf[dt] = *(const short8*)(vp2 + dt * 1024 + lane * 8);
        __builtin_amdgcn_sched_barrier(0);

        // 2) async-stage next step's mask into the other buffer (zero VGPR)
        if (s < 63) {
            int* dst = swv + (((s + 1) & 1) << 11);
            const int* sp = lane_src + (long)(s + 1) * 32;
#pragma unroll
            for (int i = 0; i < 8; ++i)
                gll16(sp + i * 16384, dst + i * 256);
        }

        // 3) counted wait: retire everything except the 8 just-issued gll
        asm volatile("s_waitcnt vmcnt(8)" ::: "memory");
        __builtin_amdgcn_sched_barrier(0);

        // 4) compute on buf[s&1]
        const int* rbuf = swv + ((s & 1) << 11);
#pragma unroll
        for (int qt = 0; qt < 4; ++qt) {
            f32x4 z = (f32x4){0.f, 0.f, 0.f, 0.f};
            f32x4 st0 = MFMA(kf[0][1], qf[qt][1], MFMA(kf[0][0], qf[qt][0], z));
            f32x4 st1 = MFMA(kf[1][1], qf[qt][1], MFMA(kf[1][0], qf[qt][0], z));
            // kv = s*32 + kt*16 + g*4 + r, q = q0 + qt*16 + c (log2e-scaled)

            int row = qt * 16 + c;
            i32x4 mk0 = *(const i32x4*)(rbuf + row * 32 + gs0);
            i32x4 mk1 = *(const i32x4*)(rbuf + row * 32 + gs1);

            float p0[4], p1[4], ssum = 0.f;
#pragma unroll
            for (int r = 0; r < 4; ++r) {
                float v0 = (mk0[r] != 0) ? st0[r] : 0.0f;   // masked -> exp2(0)=1
                float v1 = (mk1[r] != 0) ? st1[r] : 0.0f;
                float e0 = exp2f(v0), e1 = exp2f(v1);
                p0[r] = e0; p1[r] = e1;
                ssum += e0 + e1;
            }
            lsum[qt] += ssum;

            short8 pb;
            pb[0] = f2bf(p0[0]); pb[1] = f2bf(p0[1]); pb[2] = f2bf(p0[2]); pb[3] = f2bf(p0[3]);
            pb[4] = f2bf(p1[0]); pb[5] = f2bf(p1[1]); pb[6] = f2bf(p1[2]); pb[7] = f2bf(p1[3]);

#pragma unroll
            for (int dt = 0; dt < 4; ++dt)
                acc[qt][dt] = MFMA(vf[dt], pb, acc[qt][dt]);
        }
    }

    // epilogue: reduce row sums across g-groups, normalize, store
#pragma unroll
    for (int qt = 0; qt < 4; ++qt) {
        float t0 = lsum[qt];
        t0 += __shfl_xor(t0, 16);
        t0 += __shfl_xor(t0, 32);
        float inv = 1.0f / t0;
        float* orow = obase + (long)(q0 + qt * 16 + c) * HD_;
#pragma unroll
        for (int dt = 0; dt < 4; ++dt) {
            f32x4 o = acc[qt][dt] * inv;
            __builtin_nontemporal_store(o, (f32x4*)(orow + dt * 16 + g * 4));
        }
    }
}

// ---- fallback (only if ws too small): round-1 style fused kernel ----
__global__ __launch_bounds__(256, 2)
void attn_fwd(const float* __restrict__ Q, const float* __restrict__ K,
              const float* __restrict__ V, const int* __restrict__ M,
              float* __restrict__ O)
{
    const float QSCALE = 0.125f * 1.44269504088896340736f;
    int orig = blockIdx.x;
    int wg   = (orig & 7) * 64 + (orig >> 3);
    int bh   = wg >> 3, qb = wg & 7;
    int b    = bh >> 4, h = bh & 15;
    int lane = threadIdx.x & 63, wave = threadIdx.x >> 6;
    int g = lane >> 4, c = lane & 15;
    int q0 = qb * 256 + wave * 64;

    const float* qbase = Q + (long)(b * S_) * HD_ + h * 64;
    const float* kbase = K + (long)(b * S_) * HD_ + h * 64;
    const float* vbase = V + (long)(b * S_) * HD_ + h * 64;
    const int*   mbase = M + ((long)bh << 22);
    float*       obase = O + (long)(b * S_) * HD_ + h * 64;

    short8 qf[4][2];
#pragma unroll
    for (int qt = 0; qt < 4; ++qt) {
        const float* qr = qbase + (long)(q0 + qt * 16 + c) * HD_;
#pragma unroll
        for (int hf = 0; hf < 2; ++hf) {
            f32x4 x0 = *(const f32x4*)(qr + hf * 32 + g * 8);
            f32x4 x1 = *(const f32x4*)(qr + hf * 32 + g * 8 + 4);
            short8 t;
            t[0] = f2bf(x0[0] * QSCALE); t[1] = f2bf(x0[1] * QSCALE);
            t[2] = f2bf(x0[2] * QSCALE); t[3] = f2bf(x0[3] * QSCALE);
            t[4] = f2bf(x1[0] * QSCALE); t[5] = f2bf(x1[1] * QSCALE);
            t[6] = f2bf(x1[2] * QSCALE); t[7] = f2bf(x1[3] * QSCALE);
            qf[qt][hf] = t;
        }
    }

    f32x4 acc[4][4];
#pragma unroll
    for (int qt = 0; qt < 4; ++qt)
#pragma unroll
        for (int dt = 0; dt < 4; ++dt) acc[qt][dt] = (f32x4){0.f, 0.f, 0.f, 0.f};
    float lsum[4] = {0.f, 0.f, 0.f, 0.f};

#pragma unroll 1
    for (int step = 0; step < 32; ++step) {
        int kv0 = step * 64;
        short8 kf[4][2];
#pragma unroll
        for (int kt = 0; kt < 4; ++kt) {
            const float* kr = kbase + (long)(kv0 + kt * 16 + c) * HD_;
#pragma unroll
            for (int hf = 0; hf < 2; ++hf) {
                f32x4 x0 = *(const f32x4*)(kr + hf * 32 + g * 8);
                f32x4 x1 = *(const f32x4*)(kr + hf * 32 + g * 8 + 4);
                short8 t;
                t[0] = f2bf(x0[0]); t[1] = f2bf(x0[1]); t[2] = f2bf(x0[2]); t[3] = f2bf(x0[3]);
                t[4] = f2bf(x1[0]); t[5] = f2bf(x1[1]); t[6] = f2bf(x1[2]); t[7] = f2bf(x1[3]);
                kf[kt][hf] = t;
            }
        }
        short8 vf[4][2];
#pragma unroll
        for (int hf = 0; hf < 2; ++hf) {
            const float* vr[8];
#pragma unroll
            for (int i = 0; i < 4; ++i) {
                vr[i]     = vbase + (long)(kv0 + hf * 32 + g * 4 + i) * HD_ + c;
                vr[4 + i] = vbase + (long)(kv0 + hf * 32 + 16 + g * 4 + i) * HD_ + c;
            }
#pragma unroll
            for (int dt = 0; dt < 4; ++dt) {
                short8 t;
#pragma unroll
                for (int i = 0; i < 8; ++i) t[i] = f2bf(vr[i][dt * 16]);
                vf[dt][hf] = t;
            }
        }
#pragma unroll
        for (int qt = 0; qt < 4; ++qt) {
            f32x4 st[4];
#pragma unroll
            for (int kt = 0; kt < 4; ++kt) {
                f32x4 z = (f32x4){0.f, 0.f, 0.f, 0.f};
                z = MFMA(kf[kt][0], qf[qt][0], z);
                z = MFMA(kf[kt][1], qf[qt][1], z);
                st[kt] = z;
            }
            const int* mrp = mbase + ((long)(q0 + qt * 16 + c) << 11) + kv0 + g * 4;
            float p[4][4];
            float s = 0.f;
#pragma unroll
            for (int kt = 0; kt < 4; ++kt) {
                i32x4 mkv = *(const i32x4*)(mrp + kt * 16);
#pragma unroll
                for (int r = 0; r < 4; ++r) {
                    float val = (mkv[r] != 0) ? st[kt][r] : 0.0f;
                    float e = exp2f(val);
                    p[kt][r] = e;
                    s += e;
                }
            }
            lsum[qt] += s;
            short8 pb0, pb1;
            pb0[0] = f2bf(p[0][0]); pb0[1] = f2bf(p[0][1]); pb0[2] = f2bf(p[0][2]); pb0[3] = f2bf(p[0][3]);
            pb0[4] = f2bf(p[1][0]); pb0[5] = f2bf(p[1][1]); pb0[6] = f2bf(p[1][2]); pb0[7] = f2bf(p[1][3]);
            pb1[0] = f2bf(p[2][0]); pb1[1] = f2bf(p[2][1]); pb1[2] = f2bf(p[2][2]); pb1[3] = f2bf(p[2][3]);
            pb1[4] = f2bf(p[3][0]); pb1[5] = f2bf(p[3][1]); pb1[6] = f2bf(p[3][2]); pb1[7] = f2bf(p[3][3]);
#pragma unroll
            for (int dt = 0; dt < 4; ++dt) {
                acc[qt][dt] = MFMA(vf[dt][0], pb0, acc[qt][dt]);
                acc[qt][dt] = MFMA(vf[dt][1], pb1, acc[qt][dt]);
            }
        }
    }
#pragma unroll
    for (int qt = 0; qt < 4; ++qt) {
        float t0 = lsum[qt];
        t0 += __shfl_xor(t0, 16);
        t0 += __shfl_xor(t0, 32);
        float inv = 1.0f / t0;
        float* orow = obase + (long)(q0 + qt * 16 + c) * HD_;
#pragma unroll
        for (int dt = 0; dt < 4; ++dt) {
            f32x4 o = acc[qt][dt] * inv;
            *(f32x4*)(orow + dt * 16 + g * 4) = o;
        }
    }
}

extern "C" void kernel_launch(void* const* d_in, const int* in_sizes, int n_in,
                              void* d_out, int out_size, void* d_ws, size_t ws_size,
                              hipStream_t stream) {
    const float* q = (const float*)d_in[0];
    const float* k = (const float*)d_in[1];
    const float* v = (const float*)d_in[2];
    const int*   m = (const int*)d_in[3];
    float* out = (float*)d_out;

    size_t need = (size_t)2 * KP_ELEMS * sizeof(short);   // 32 MiB
    if (ws_size >= need) {
        short* Kp = (short*)d_ws;
        short* Vp = Kp + KP_ELEMS;
        prepack_kv<<<dim3(4096), dim3(256), 0, stream>>>(k, v, Kp, Vp);
        attn_gll<<<dim3(512), dim3(256), 0, stream>>>(q, Kp, Vp, m, out);
    } else {
        attn_fwd<<<dim3(512), dim3(256), 0, stream>>>(q, k, v, m, out);
    }
}